// Round 3
// baseline (1789.981 us; speedup 1.0000x reference)
//
#include <hip/hip_runtime.h>
#include <hip/hip_bf16.h>
#include <stdint.h>

// R3: wave tile 128x128 (BM=BN=256, 4 waves), 32x32x16 MFMA, single-barrier
//     double-buffered K-loop (prefetch tile n+1 via global_load_lds, compute
//     tile n, one __syncthreads). 1 block/CU (VGPR-bound) — overlap comes from
//     the explicit pipeline, not occupancy.
// out[k,b,d] = sum_i s(k,i) * (x_i @ W[:, j(k,i)]) + bias; (3,0,0) Clifford. 1.10 TFLOP.

#define MB 8
#define BATCH 2048
#define DIN 2048
#define DD 2048
#define NR (MB * BATCH)
#define UU (MB * DD)

#define BM 256
#define BN 256
#define BK 32
#define NITER (MB * (DIN / BK))  // 512

typedef __attribute__((ext_vector_type(8))) __bf16 bf16x8;
typedef __attribute__((ext_vector_type(16))) float f32x16;
typedef __attribute__((ext_vector_type(4))) unsigned int u32x4;

__constant__ int c_jmap[8][8] = {
    {0, 1, 2, 3, 4, 5, 6, 7},
    {1, 0, 4, 5, 2, 3, 7, 6},
    {2, 4, 0, 6, 1, 7, 3, 5},
    {3, 5, 6, 0, 7, 1, 2, 4},
    {4, 2, 1, 7, 0, 6, 5, 3},
    {5, 3, 7, 1, 6, 0, 4, 2},
    {6, 7, 3, 2, 5, 4, 0, 1},
    {7, 6, 5, 4, 3, 2, 1, 0}};
#define NEG 0x80008000u
__constant__ unsigned int c_smask[8][8] = {
    {0, 0, 0, 0, NEG, NEG, NEG, NEG},
    {0, 0, NEG, NEG, 0, 0, NEG, NEG},
    {0, 0, 0, NEG, NEG, 0, 0, 0},
    {0, 0, 0, 0, NEG, NEG, NEG, NEG},
    {0, 0, NEG, 0, 0, NEG, 0, 0},
    {0, 0, NEG, NEG, 0, 0, NEG, NEG},
    {0, 0, 0, NEG, NEG, 0, 0, 0},
    {0, 0, NEG, 0, 0, NEG, 0, 0}};

__device__ __forceinline__ unsigned short f2bf(float f) {
  unsigned int u = __float_as_uint(f);
  u = (u + 0x7FFFu + ((u >> 16) & 1u)) >> 16;  // RNE
  return (unsigned short)u;
}

__global__ void cast_x_kernel(const float* __restrict__ x,
                              unsigned short* __restrict__ o, int n8) {
  int i = blockIdx.x * blockDim.x + threadIdx.x;
  if (i >= n8) return;
  float4 a = ((const float4*)x)[i * 2];
  float4 b = ((const float4*)x)[i * 2 + 1];
  ushort s[8] = {f2bf(a.x), f2bf(a.y), f2bf(a.z), f2bf(a.w),
                 f2bf(b.x), f2bf(b.y), f2bf(b.z), f2bf(b.w)};
  u32x4 p;
  p[0] = (unsigned)s[0] | ((unsigned)s[1] << 16);
  p[1] = (unsigned)s[2] | ((unsigned)s[3] << 16);
  p[2] = (unsigned)s[4] | ((unsigned)s[5] << 16);
  p[3] = (unsigned)s[6] | ((unsigned)s[7] << 16);
  ((u32x4*)o)[i] = p;
}

// W [DIN][UU] fp32 -> Wt [UU][DIN] bf16. 64x64 tiles, 256 threads.
__global__ void transpose_cast_w(const float* __restrict__ W,
                                 unsigned short* __restrict__ Wt) {
  __shared__ float tile[64][65];
  const int tid = threadIdx.x;
  const int c0 = blockIdx.x * 64;
  const int r0 = blockIdx.y * 64;
  {
    const int row = tid >> 4;
    const int col = (tid & 15) * 4;
#pragma unroll
    for (int j = 0; j < 4; ++j) {
      float4 v = *(const float4*)&W[(size_t)(r0 + row + j * 16) * UU + c0 + col];
      tile[row + j * 16][col + 0] = v.x;
      tile[row + j * 16][col + 1] = v.y;
      tile[row + j * 16][col + 2] = v.z;
      tile[row + j * 16][col + 3] = v.w;
    }
  }
  __syncthreads();
  {
    const int rc = (tid & 7) * 8;
    int c = tid >> 3;
#pragma unroll
    for (int h = 0; h < 2; ++h, c += 32) {
      u32x4 p;
#pragma unroll
      for (int w = 0; w < 4; ++w) {
        unsigned lo = f2bf(tile[rc + w * 2][c]);
        unsigned hi = f2bf(tile[rc + w * 2 + 1][c]);
        p[w] = lo | (hi << 16);
      }
      *(u32x4*)&Wt[(size_t)(c0 + c) * DIN + r0 + rc] = p;
    }
  }
}

__device__ __forceinline__ void gl_lds16(const void* g, void* l) {
  __builtin_amdgcn_global_load_lds((__attribute__((address_space(1))) void*)g,
                                   (__attribute__((address_space(3))) void*)l,
                                   16, 0, 0);
}

union FragU {
  u32x4 u;
  bf16x8 v;
};

// grid (DD/BN=8, BATCH/BM=8, 8) = 512 blocks; block 256 = 4 waves (2x2),
// wave tile 128x128 via 4x4 32x32x16 MFMA accumulators.
__global__ __launch_bounds__(256, 1) void ga_gemm(
    const unsigned short* __restrict__ Xb,   // [NR][DIN] bf16
    const unsigned short* __restrict__ Wt,   // [UU][DIN] bf16 (= W^T)
    const float* __restrict__ bias,          // [UU]
    float* __restrict__ out) {               // [NR][DD] fp32
  // A/B tiles 256 rows x 32 k = 16 KB each, double buffered: 64 KB total.
  __shared__ u32x4 ldsA[2][BM * BK / 8];  // [2][1024]
  __shared__ u32x4 ldsB[2][BN * BK / 8];  // [2][1024]

  const int tid = threadIdx.x;
  const int kb = blockIdx.z;
  const int tm = blockIdx.y;
  const int tn = blockIdx.x;
  const int wid = tid >> 6;
  const int lane = tid & 63;
  const int wm = wid & 1;   // 0/1 -> which 128-row half
  const int wn = wid >> 1;  // 0/1 -> which 128-col half
  const int l31 = lane & 31;
  const int half = lane >> 5;

  f32x16 acc[4][4] = {};

  // Staging: slot L (0..1023) holds 16B chunk (m = L>>2, c = (L&3)^(m&3)) of
  // the tile; XOR swizzle on the GLOBAL source address so LDS dest stays
  // lane-contiguous for global_load_lds, and fragment ds_read_b128 is
  // bank-balanced (8 dwords/bank).
  int offG[4];  // element offset of this thread's chunk within a tile
#pragma unroll
  for (int t = 0; t < 4; ++t) {
    const int L = t * 256 + tid;
    const int m = L >> 2;
    const int c = (L & 3) ^ (m & 3);
    offG[t] = m * DIN + c * 8;
  }
  const int ldsBase = tid & 192;  // wid*64 — wave-uniform LDS dest base

  auto stage = [&](int buf, int it) {
    const int iseg = it >> 6;
    const int k0 = (it & 63) * BK;
    const size_t abase = (size_t)(iseg * BATCH + tm * BM) * DIN + k0;
    const size_t bbase = (size_t)(c_jmap[kb][iseg] * DD + tn * BN) * DIN + k0;
#pragma unroll
    for (int t = 0; t < 4; ++t) {
      gl_lds16(Xb + abase + offG[t], &ldsA[buf][t * 256 + ldsBase]);
      gl_lds16(Wt + bbase + offG[t], &ldsB[buf][t * 256 + ldsBase]);
    }
  };

  stage(0, 0);
  __syncthreads();

  for (int it = 0; it < NITER; ++it) {
    const int cur = it & 1;
    const int nit = (it + 1 < NITER) ? it + 1 : NITER - 1;
    stage(cur ^ 1, nit);  // async prefetch; drained by the barrier BELOW,
                          // i.e. after a full compute phase of overlap

    const unsigned smask = c_smask[kb][it >> 6];
#pragma unroll
    for (int s = 0; s < 2; ++s) {  // two K=16 steps per BK=32 tile
      FragU af[4], bq[4];
      const int p = s * 2 + half;  // k-chunk index 0..3
#pragma unroll
      for (int mt = 0; mt < 4; ++mt) {
        const int ml = wm * 128 + mt * 32 + l31;
        af[mt].u = ldsA[cur][ml * 4 + (p ^ (ml & 3))];
      }
      if (smask) {  // block-uniform: negate A fragments
#pragma unroll
        for (int mt = 0; mt < 4; ++mt) af[mt].u ^= smask;
      }
#pragma unroll
      for (int nt = 0; nt < 4; ++nt) {
        const int nl = wn * 128 + nt * 32 + l31;
        bq[nt].u = ldsB[cur][nl * 4 + (p ^ (nl & 3))];
      }
#pragma unroll
      for (int mt = 0; mt < 4; ++mt)
#pragma unroll
        for (int nt = 0; nt < 4; ++nt)
          acc[mt][nt] = __builtin_amdgcn_mfma_f32_32x32x16_bf16(
              af[mt].v, bq[nt].v, acc[mt][nt], 0, 0, 0);
    }
    __syncthreads();
  }

  // C/D layout (m74/m101): col = lane&31, row = (reg&3) + 8*(reg>>2) + 4*(lane>>5)
#pragma unroll
  for (int nt = 0; nt < 4; ++nt) {
    const int gcol = tn * BN + wn * 128 + nt * 32 + l31;
    const float bv = bias[kb * DD + gcol];
#pragma unroll
    for (int mt = 0; mt < 4; ++mt) {
      const int rbase = tm * BM + wm * 128 + mt * 32 + 4 * half;
#pragma unroll
      for (int r = 0; r < 16; ++r) {
        const int grow = rbase + (r & 3) + 8 * (r >> 2);
        out[(size_t)(kb * BATCH + grow) * DD + gcol] = acc[mt][nt][r] + bv;
      }
    }
  }
}

extern "C" void kernel_launch(void* const* d_in, const int* in_sizes, int n_in,
                              void* d_out, int out_size, void* d_ws,
                              size_t ws_size, hipStream_t stream) {
  const float* x = (const float*)d_in[0];
  const float* W = (const float*)d_in[1];
  const float* bias = (const float*)d_in[2];
  float* out = (float*)d_out;

  unsigned short* xb = (unsigned short*)d_ws;
  unsigned short* wt = xb + (size_t)NR * DIN;

  int n8 = (NR * DIN) / 8;
  cast_x_kernel<<<n8 / 256, 256, 0, stream>>>(x, xb, n8);

  dim3 tg(UU / 64, DIN / 64);
  transpose_cast_w<<<tg, 256, 0, stream>>>(W, wt);

  dim3 gg(DD / BN, BATCH / BM, MB);  // (8, 8, 8) = 512 blocks
  ga_gemm<<<gg, 256, 0, stream>>>(xb, wt, bias, out);
}